// Round 4
// baseline (2483.720 us; speedup 1.0000x reference)
//
#include <hip/hip_runtime.h>

typedef __bf16 bf16x8 __attribute__((ext_vector_type(8)));
typedef float  f32x16 __attribute__((ext_vector_type(16)));

// fp32 -> bf16 bits, round-to-nearest-even
__device__ __forceinline__ unsigned short f2bf_bits(float f) {
    unsigned int u = __builtin_bit_cast(unsigned int, f);
    u += 0x7FFFu + ((u >> 16) & 1u);
    return (unsigned short)(u >> 16);
}

// One workgroup = one channel c, 8 images (2 per wave, 4 waves). grid = 192*4 = 768 (3 blocks/CU).
// Out[ho,wo] = sum_r sum_kw  Weff[25+r-ho, kw] * Xp_r[wo+kw]
// Register-pipelined: fragments for row r+1 are ds_read-issued BEFORE row r's MFMA burst;
// rowbuf writes for row r+2 issued AFTER the burst. Ds-op FIFO (same wave) makes this safe.
__global__ void __launch_bounds__(256, 3) dw5_51_kernel(
    const float* __restrict__ x,
    const float* __restrict__ w5,
    const float* __restrict__ w51,
    float* __restrict__ out)
{
    // weights, granule-major: g=kw/8 (8) x 128 rows x 8 elems
    __shared__ unsigned short wlds[8 * 1024];             // 16384 B
    // row buffers: 4 waves x 2 imgs x 2 phases x (8 shift-copies x 136 elems)
    __shared__ unsigned short rowbuf[4][2][2][1088];      // 34816 B (total 51200 B -> 3 blocks/CU)

    const int tid = threadIdx.x;
    const int wg  = blockIdx.x;
    const int c   = wg >> 2;      // 0..191
    const int bg  = wg & 3;       // 0..3

    // ---- stage effective weights, reversed rows, granule-major ----
    {
        const int s    = tid >> 1;          // 0..127
        const int half = tid & 1;
        const int kh   = 88 - s;
        const bool rowok = (kh >= 0) && (kh <= 50);
        #pragma unroll
        for (int j = 0; j < 32; ++j) {
            const int kw = half * 32 + j;
            float v = 0.0f;
            if (rowok && kw <= 50) {
                v = w51[c * 2601 + kh * 51 + kw];
                if (kh >= 23 && kh < 28 && kw >= 23 && kw < 28)
                    v += w5[c * 25 + (kh - 23) * 5 + (kw - 23)];
            }
            wlds[(kw >> 3) * 1024 + s * 8 + (kw & 7)] = f2bf_bits(v);
        }
    }

    const int lane = tid & 63;
    const int wv   = tid >> 6;        // wave 0..3
    const int b0   = bg * 8 + wv * 2; // first image batch index
    const int n32  = lane & 31;
    const int gg   = lane >> 5;
    const int q    = lane & 7;
    const int u8   = n32 >> 3;

    // zero this wave's row buffers (pad must be 0)
    {
        unsigned int* z = (unsigned int*)&rowbuf[wv][0][0][0];
        #pragma unroll
        for (int i = 0; i < 34; ++i) z[lane + 64 * i] = 0u;
    }
    __syncthreads();

    const long ib0 = ((long)b0 * 192 + c) * 4096;
    const long ib1 = ((long)(b0 + 1) * 192 + c) * 4096;
    const float* xr0 = x + ib0 + lane;
    const float* xr1 = x + ib1 + lane;
    float* outp0 = out + ib0;
    float* outp1 = out + ib1;

    const int bidx  = 136 * q + 8 * u8 + 8 * gg;  // B-read base (elems); +16*t
    const int wbase = lane + 25;                  // write elem = wbase + 135*qq
    const int abase = gg * 1024 + n32 * 8;        // + row*8 + ks*2048

    unsigned short* buf00 = &rowbuf[wv][0][0][0]; // img0 phase0
    unsigned short* buf10 = &rowbuf[wv][1][0][0]; // img1 phase0
    unsigned short* buf01 = &rowbuf[wv][0][1][0]; // img0 phase1
    unsigned short* buf11 = &rowbuf[wv][1][1][0]; // img1 phase1

    f32x16 acc[2][2][2] = {};                     // [img][mtile][ntile]

    auto loadA = [&](bf16x8 (&A)[2][4], int r) {
        const int s0 = ((63 - r) & 127) * 8 + abase;   // wrap keeps dead prefetch (r=64) in-range
        const int s1 = (95 - r) * 8 + abase;
        #pragma unroll
        for (int ks = 0; ks < 4; ++ks) {
            A[0][ks] = *(const bf16x8*)&wlds[s0 + ks * 2048];
            A[1][ks] = *(const bf16x8*)&wlds[s1 + ks * 2048];
        }
    };
    auto loadB = [&](bf16x8 (&D)[2][6], const unsigned short* p0, const unsigned short* p1) {
        #pragma unroll
        for (int t = 0; t < 6; ++t) {
            D[0][t] = *(const bf16x8*)&p0[bidx + 16 * t];
            D[1][t] = *(const bf16x8*)&p1[bidx + 16 * t];
        }
    };
    auto domfma = [&](bf16x8 (&A)[2][4], bf16x8 (&D)[2][6], int r) {
        if (r <= 56) {
            #pragma unroll
            for (int ks = 0; ks < 4; ++ks) {
                acc[0][0][0] = __builtin_amdgcn_mfma_f32_32x32x16_bf16(A[0][ks], D[0][ks],     acc[0][0][0], 0, 0, 0);
                acc[0][0][1] = __builtin_amdgcn_mfma_f32_32x32x16_bf16(A[0][ks], D[0][ks + 2], acc[0][0][1], 0, 0, 0);
                acc[1][0][0] = __builtin_amdgcn_mfma_f32_32x32x16_bf16(A[0][ks], D[1][ks],     acc[1][0][0], 0, 0, 0);
                acc[1][0][1] = __builtin_amdgcn_mfma_f32_32x32x16_bf16(A[0][ks], D[1][ks + 2], acc[1][0][1], 0, 0, 0);
            }
        }
        if (r >= 7) {
            #pragma unroll
            for (int ks = 0; ks < 4; ++ks) {
                acc[0][1][0] = __builtin_amdgcn_mfma_f32_32x32x16_bf16(A[1][ks], D[0][ks],     acc[0][1][0], 0, 0, 0);
                acc[0][1][1] = __builtin_amdgcn_mfma_f32_32x32x16_bf16(A[1][ks], D[0][ks + 2], acc[0][1][1], 0, 0, 0);
                acc[1][1][0] = __builtin_amdgcn_mfma_f32_32x32x16_bf16(A[1][ks], D[1][ks],     acc[1][1][0], 0, 0, 0);
                acc[1][1][1] = __builtin_amdgcn_mfma_f32_32x32x16_bf16(A[1][ks], D[1][ks + 2], acc[1][1][1], 0, 0, 0);
            }
        }
    };
    auto writerow = [&](unsigned short* p0, unsigned short* p1, float v0, float v1) {
        const unsigned short w0 = f2bf_bits(v0), w1 = f2bf_bits(v1);
        #pragma unroll
        for (int qq = 0; qq < 8; ++qq) {
            p0[wbase + 135 * qq] = w0;
            p1[wbase + 135 * qq] = w1;
        }
    };

    // ---- prologue: rows 0,1 into LDS; row-0 fragments into registers; xv holds row 2 ----
    float xv0 = xr0[0], xv1 = xr1[0];
    writerow(buf00, buf10, xv0, xv1);                     // row 0 -> phase 0
    xv0 = xr0[64]; xv1 = xr1[64];
    writerow(buf01, buf11, xv0, xv1);                     // row 1 -> phase 1
    xv0 = xr0[128]; xv1 = xr1[128];                       // row 2 data

    bf16x8 AE[2][4], AO[2][4], DE[2][6], DO[2][6];
    loadA(AE, 0);
    loadB(DE, buf00, buf10);

    #pragma unroll 1
    for (int rr = 0; rr < 64; rr += 2) {
        // ---- even: prefetch row rr+1 frags, MFMA row rr, then write row rr+2 ----
        loadA(AO, rr + 1);
        loadB(DO, buf01, buf11);                          // row rr+1 lives in phase 1
        domfma(AE, DE, rr);
        if (rr + 2 < 64) {
            writerow(buf00, buf10, xv0, xv1);             // row rr+2 -> phase 0
            if (rr + 3 < 64) { xv0 = xr0[(rr + 3) * 64]; xv1 = xr1[(rr + 3) * 64]; }
        }
        // ---- odd: prefetch row rr+2 frags, MFMA row rr+1, then write row rr+3 ----
        loadA(AE, rr + 2);
        loadB(DE, buf00, buf10);                          // row rr+2 lives in phase 0
        domfma(AO, DO, rr + 1);
        if (rr + 3 < 64) {
            writerow(buf01, buf11, xv0, xv1);             // row rr+3 -> phase 1
            if (rr + 4 < 64) { xv0 = xr0[(rr + 4) * 64]; xv1 = xr1[(rr + 4) * 64]; }
        }
    }

    // ---- epilogue: D layout (32x32): col = lane&31, row = (v&3) + 8*(v>>2) + 4*(lane>>5) ----
    #pragma unroll
    for (int v = 0; v < 16; ++v) {
        const int ho = (v & 3) + 8 * (v >> 2) + 4 * gg;
        outp0[ho * 64 + n32]             = acc[0][0][0][v];
        outp0[ho * 64 + n32 + 32]        = acc[0][0][1][v];
        outp0[(ho + 32) * 64 + n32]      = acc[0][1][0][v];
        outp0[(ho + 32) * 64 + n32 + 32] = acc[0][1][1][v];
        outp1[ho * 64 + n32]             = acc[1][0][0][v];
        outp1[ho * 64 + n32 + 32]        = acc[1][0][1][v];
        outp1[(ho + 32) * 64 + n32]      = acc[1][1][0][v];
        outp1[(ho + 32) * 64 + n32 + 32] = acc[1][1][1][v];
    }
}

extern "C" void kernel_launch(void* const* d_in, const int* in_sizes, int n_in,
                              void* d_out, int out_size, void* d_ws, size_t ws_size,
                              hipStream_t stream) {
    (void)in_sizes; (void)n_in; (void)d_ws; (void)ws_size; (void)out_size;
    const float* x   = (const float*)d_in[0];
    const float* w5  = (const float*)d_in[1];
    const float* w51 = (const float*)d_in[2];
    float* out = (float*)d_out;
    dim3 grid(192 * 4), block(256);
    hipLaunchKernelGGL(dw5_51_kernel, grid, block, 0, stream, x, w5, w51, out);
}

// Round 5
// 153.926 us; speedup vs baseline: 16.1358x; 16.1358x over previous
//
#include <hip/hip_runtime.h>

typedef __bf16 bf16x8 __attribute__((ext_vector_type(8)));
typedef float  f32x16 __attribute__((ext_vector_type(16)));

// fp32 -> bf16 bits, round-to-nearest-even
__device__ __forceinline__ unsigned short f2bf_bits(float f) {
    unsigned int u = __builtin_bit_cast(unsigned int, f);
    u += 0x7FFFu + ((u >> 16) & 1u);
    return (unsigned short)(u >> 16);
}

// One workgroup = one channel c, 4 images (1 per wave). grid = 192*8 = 1536 (6 blocks/CU, 3 even rounds).
// Out[ho,wo] = sum_r sum_kw  Weff[25+r-ho, kw] * Xp_r[wo+kw]
// Register-pipelined: row r+1's A/B fragments are ds_read BEFORE row r's MFMA burst; the LDS row
// write for r+2 comes after. Budget: acc 64 + A-dbuf 64 + B-dbuf 48 + misc ~ 200 regs < 256 cap.
__global__ void __launch_bounds__(256, 2) dw5_51_kernel(
    const float* __restrict__ x,
    const float* __restrict__ w5,
    const float* __restrict__ w51,
    float* __restrict__ out)
{
    // weights, granule-major: g=kw/8 (8) x 128 rows x 8 elems
    __shared__ unsigned short wlds[8 * 1024];          // 16384 B
    // row buffers: 4 waves x 2 phases x (8 shift-copies x 136 elems)
    __shared__ unsigned short rowbuf[4][2][1088];      // 17408 B (total 33792 B)

    const int tid = threadIdx.x;
    const int wg  = blockIdx.x;
    const int c   = wg >> 3;      // 0..191
    const int bg  = wg & 7;       // 0..7

    // ---- stage effective weights, reversed rows, granule-major ----
    // LDS row s holds Weff row kh = 88 - s; elem kw at wlds[(kw>>3)*1024 + s*8 + (kw&7)]
    {
        const int s    = tid >> 1;          // 0..127
        const int half = tid & 1;
        const int kh   = 88 - s;
        const bool rowok = (kh >= 0) && (kh <= 50);
        #pragma unroll
        for (int j = 0; j < 32; ++j) {
            const int kw = half * 32 + j;
            float v = 0.0f;
            if (rowok && kw <= 50) {
                v = w51[c * 2601 + kh * 51 + kw];
                if (kh >= 23 && kh < 28 && kw >= 23 && kw < 28)
                    v += w5[c * 25 + (kh - 23) * 5 + (kw - 23)];
            }
            wlds[(kw >> 3) * 1024 + s * 8 + (kw & 7)] = f2bf_bits(v);
        }
    }

    const int lane = tid & 63;
    const int wv   = tid >> 6;        // wave 0..3
    const int b    = bg * 4 + wv;     // batch 0..31
    const int n32  = lane & 31;
    const int gg   = lane >> 5;
    const int q    = lane & 7;
    const int u8   = n32 >> 3;

    // zero this wave's row buffers (pad must be 0; data region rewritten every row)
    {
        unsigned int* z = (unsigned int*)&rowbuf[wv][0][0];
        #pragma unroll
        for (int i = 0; i < 17; ++i) z[lane + 64 * i] = 0u;
    }
    __syncthreads();

    const long imgbase = ((long)b * 192 + c) * 4096;
    const float* xrow = x + imgbase + lane;
    float* outp = out + imgbase;

    const int bidx  = 136 * q + 8 * u8 + 8 * gg;  // B-read base (elems); +16*t, t=0..5
    const int wbase = lane + 25;                  // write elem = wbase + 135*qq
    const int abase = gg * 1024 + n32 * 8;        // + srow*8 + ks*2048

    unsigned short* buf0 = &rowbuf[wv][0][0];
    unsigned short* buf1 = &rowbuf[wv][1][0];

    f32x16 acc00 = {}, acc01 = {}, acc10 = {}, acc11 = {};

    auto loadA = [&](bf16x8 (&A)[8], int r) {
        const int rc = r & 63;                       // r=64 prefetch is dead; keep in-range
        const int s0 = (63 - rc) * 8 + abase;        // m-tile 0 rows
        const int s1 = (95 - rc) * 8 + abase;        // m-tile 1 rows (kh<0 rows staged as 0)
        #pragma unroll
        for (int ks = 0; ks < 4; ++ks) {
            A[ks]     = *(const bf16x8*)&wlds[s0 + ks * 2048];
            A[4 + ks] = *(const bf16x8*)&wlds[s1 + ks * 2048];
        }
    };
    auto loadB = [&](bf16x8 (&D)[6], const unsigned short* p) {
        #pragma unroll
        for (int t = 0; t < 6; ++t) D[t] = *(const bf16x8*)&p[bidx + 16 * t];
    };
    auto domfma = [&](bf16x8 (&A)[8], bf16x8 (&D)[6], int r) {
        __builtin_amdgcn_s_setprio(1);
        if (r <= 56) {
            #pragma unroll
            for (int ks = 0; ks < 4; ++ks) {
                acc00 = __builtin_amdgcn_mfma_f32_32x32x16_bf16(A[ks], D[ks],     acc00, 0, 0, 0);
                acc01 = __builtin_amdgcn_mfma_f32_32x32x16_bf16(A[ks], D[ks + 2], acc01, 0, 0, 0);
            }
        }
        if (r >= 7) {
            #pragma unroll
            for (int ks = 0; ks < 4; ++ks) {
                acc10 = __builtin_amdgcn_mfma_f32_32x32x16_bf16(A[4 + ks], D[ks],     acc10, 0, 0, 0);
                acc11 = __builtin_amdgcn_mfma_f32_32x32x16_bf16(A[4 + ks], D[ks + 2], acc11, 0, 0, 0);
            }
        }
        __builtin_amdgcn_s_setprio(0);
    };
    auto writerow = [&](unsigned short* p, float v) {
        const unsigned short w0 = f2bf_bits(v);
        #pragma unroll
        for (int qq = 0; qq < 8; ++qq) p[wbase + 135 * qq] = w0;
    };

    // ---- prologue: rows 0,1 -> LDS; row-0 fragments -> registers; xv = row 2 ----
    float xv = xrow[0];
    writerow(buf0, xv);
    xv = xrow[64];
    writerow(buf1, xv);
    xv = xrow[128];

    bf16x8 AE[8], AO[8], DE[6], DO[6];
    loadA(AE, 0);
    loadB(DE, buf0);

    #pragma unroll 1
    for (int rr = 0; rr < 64; rr += 2) {
        // ---- even: prefetch row rr+1 frags, MFMA row rr, write row rr+2 ----
        loadA(AO, rr + 1);
        loadB(DO, buf1);                          // row rr+1 lives in phase 1
        domfma(AE, DE, rr);
        if (rr + 2 < 64) {
            writerow(buf0, xv);                   // row rr+2 -> phase 0
            if (rr + 3 < 64) xv = xrow[(rr + 3) * 64];
        }
        // ---- odd: prefetch row rr+2 frags (reads follow the write in ds-FIFO), MFMA row rr+1 ----
        loadA(AE, rr + 2);
        loadB(DE, buf0);                          // row rr+2 lives in phase 0
        domfma(AO, DO, rr + 1);
        if (rr + 3 < 64) {
            writerow(buf1, xv);                   // row rr+3 -> phase 1
            if (rr + 4 < 64) xv = xrow[(rr + 4) * 64];
        }
    }

    // ---- epilogue: D layout (32x32): col = lane&31, row = (v&3) + 8*(v>>2) + 4*(lane>>5) ----
    #pragma unroll
    for (int v = 0; v < 16; ++v) {
        const int ho = (v & 3) + 8 * (v >> 2) + 4 * gg;
        outp[ho * 64 + n32]             = acc00[v];
        outp[ho * 64 + n32 + 32]        = acc01[v];
        outp[(ho + 32) * 64 + n32]      = acc10[v];
        outp[(ho + 32) * 64 + n32 + 32] = acc11[v];
    }
}

extern "C" void kernel_launch(void* const* d_in, const int* in_sizes, int n_in,
                              void* d_out, int out_size, void* d_ws, size_t ws_size,
                              hipStream_t stream) {
    (void)in_sizes; (void)n_in; (void)d_ws; (void)ws_size; (void)out_size;
    const float* x   = (const float*)d_in[0];
    const float* w5  = (const float*)d_in[1];
    const float* w51 = (const float*)d_in[2];
    float* out = (float*)d_out;
    dim3 grid(192 * 8), block(256);
    hipLaunchKernelGGL(dw5_51_kernel, grid, block, 0, stream, x, w5, w51, out);
}